// Round 4
// baseline (16031.891 us; speedup 1.0000x reference)
//
#include <hip/hip_runtime.h>
#include <stdint.h>

// HardLSTM R4: data-as-flag. h published as dword (bf16_h<<16 | step_tag) via
// L3-coherent (sc0 sc1) stores; consumers poll their own chunk of the h tile
// until all tags match, strip into LDS. One barrier/step, no fences, no flags,
// no producer-side vmcnt drain. 2 groups x 10 wgs x 512 thr as R3.

#define T_STEPS 2000
#define BATCH   32
#define IDIM    320
#define HDIM    320
#define NWG     20
#define WPG     10
#define NTH     512
#define GB      16
#define UPW     32
#define LDK     324            // LDS row stride (elems): 648B = 2 banks -> spread
#define GSZ     (GB*HDIM)      // 5120 dwords: one group's h slice
#define SSZ     (BATCH*HDIM)   // 10240 dwords: one slot

typedef __attribute__((ext_vector_type(8))) short short8;
typedef __attribute__((ext_vector_type(4))) float f32x4;
typedef __attribute__((ext_vector_type(4))) unsigned short ushort4v;
typedef __attribute__((ext_vector_type(4))) unsigned int uint32x4;

static __device__ __forceinline__ unsigned short f2bf(float f) {
    uint32_t u = __float_as_uint(f);
    u += 0x7FFFu + ((u >> 16) & 1u);   // RTNE
    return (unsigned short)(u >> 16);
}
static __device__ __forceinline__ float bf2f(unsigned short s) {
    return __uint_as_float(((uint32_t)s) << 16);
}
static __device__ __forceinline__ float sat01(float v)  { return fminf(fmaxf(v, 0.f), 1.f); }
static __device__ __forceinline__ float clamp1(float v) { return fminf(fmaxf(v, -1.f), 1.f); }

static __device__ __forceinline__ void st_dword_l3(uint32_t* p, uint32_t v) {
    asm volatile("global_store_dword %0, %1, off sc0 sc1" :: "v"(p), "v"(v) : "memory");
}

static __device__ __forceinline__ void cvt_store(unsigned short* hi_p,
                                                 unsigned short* lo_p, float4 v) {
    ushort4v hi, lo;
    hi[0] = f2bf(v.x); lo[0] = f2bf(v.x - bf2f(hi[0]));
    hi[1] = f2bf(v.y); lo[1] = f2bf(v.y - bf2f(hi[1]));
    hi[2] = f2bf(v.z); lo[2] = f2bf(v.z - bf2f(hi[2]));
    hi[3] = f2bf(v.w); lo[3] = f2bf(v.w - bf2f(hi[3]));
    *(ushort4v*)hi_p = hi;
    *(ushort4v*)lo_p = lo;
}

__global__ __launch_bounds__(NTH, 2)
void hard_lstm(const float* __restrict__ x, const float* __restrict__ w_ih,
               const float* __restrict__ w_hh, const float* __restrict__ b_ih,
               const float* __restrict__ b_hh, float* __restrict__ out,
               uint32_t* __restrict__ hb32)
{
    __shared__ __align__(16) unsigned short xb[2][2][GB][LDK];  // x tile [slot][hi/lo]
    __shared__ __align__(16) unsigned short hbl[2][GB][LDK];    // h tile [slot]

    const int tid  = threadIdx.x;
    const int wgg  = blockIdx.x;
    const int grp  = wgg / WPG;
    const int wgl  = wgg % WPG;
    const int wave = tid >> 6;
    const int lane = tid & 63;
    const int col  = lane & 15;    // MFMA A-row / B-col (batch within group)
    const int q    = lane >> 4;    // k-chunk / output row-quad

    // ---- A fragments (weights) -> registers, bf16 hi/lo, full K=640 ----
    short8 ahi[20], alo[20];
    {
        const int jA   = wgl * UPW + wave * 4 + (col >> 2);
        const int grow = (col & 3) * HDIM + jA;
        const float* wi = w_ih + (size_t)grow * IDIM;
        const float* wh = w_hh + (size_t)grow * HDIM;
        #pragma unroll
        for (int s = 0; s < 20; ++s) {
            #pragma unroll
            for (int jj = 0; jj < 8; ++jj) {
                int k = s * 32 + q * 8 + jj;
                float w = (k < IDIM) ? wi[k] : wh[k - IDIM];
                unsigned short hi = f2bf(w);
                ahi[s][jj] = (short)hi;
                alo[s][jj] = (short)f2bf(w - bf2f(hi));
            }
        }
    }

    const int jOut = wgl * UPW + wave * 4 + q;   // hidden unit owned by this lane
    const int bOut = grp * GB + col;             // global batch owned by this lane
    float bias4[4];
    #pragma unroll
    for (int v = 0; v < 4; ++v)
        bias4[v] = b_ih[v * HDIM + jOut] + b_hh[v * HDIM + jOut];

    // staging chunks: 1280 x (16B) over [16][320]; thread gets c0,c1(,c2)
    const int c0 = tid, c1 = tid + NTH, c2 = tid + 2 * NTH;
    const int b0 = c0 / 80, k0 = (c0 % 80) * 4;
    const int b1 = c1 / 80, k1 = (c1 % 80) * 4;
    const int b2 = c2 / 80, k2 = (c2 % 80) * 4;
    const bool has2 = (tid < 256);

    uint32_t* hSelf0 = hb32 + grp * GSZ + col * HDIM + jOut;  // + slot*SSZ
    const uint32_t* hPollBase = hb32 + grp * GSZ;             // + slot*SSZ + c*4

    // ---------- pre-loop: publish h(0)=0 (tag 1), stage x(0) ----------
    st_dword_l3(hSelf0, 1u);   // hi16 = bf16(0) = 0, tag = 1
    {
        const float4* xs = (const float4*)(x + (size_t)(grp * GB) * IDIM);
        float4 v0 = xs[c0], v1 = xs[c1], v2 = {};
        if (has2) v2 = xs[c2];
        cvt_store(&xb[0][0][b0][k0], &xb[0][1][b0][k0], v0);
        cvt_store(&xb[0][0][b1][k1], &xb[0][1][b1][k1], v1);
        if (has2) cvt_store(&xb[0][0][b2][k2], &xb[0][1][b2][k2], v2);
    }

    float c_state = 0.f;

    #pragma unroll 1
    for (int t = 0; t < T_STEPS; ++t) {
        const int slot  = t & 1;
        const int slotn = slot ^ 1;

        // ---- x(t+1) prefetch (cached path; consumed after gate math) ----
        float4 xr0 = {}, xr1 = {}, xr2 = {};
        const bool havex = (t + 1 < T_STEPS);
        if (havex) {
            const float4* xs = (const float4*)(x + ((size_t)(t + 1) * BATCH + grp * GB) * IDIM);
            xr0 = xs[c0]; xr1 = xs[c1];
            if (has2) xr2 = xs[c2];
        }

        // ---- poll own h(t) chunks until every tag == t+1 (data IS the flag) ----
        uint32x4 a0, a1, a2;
        {
            const uint32_t tgt = (uint32_t)(t + 1);
            const uint32_t* pb = hPollBase + (size_t)slot * SSZ;
            const uint32_t* p0 = pb + c0 * 4;
            const uint32_t* p1 = pb + c1 * 4;
            const uint32_t* p2 = pb + (has2 ? c2 * 4 : c0 * 4);
            uint32_t mm;
            do {
                asm volatile(
                    "global_load_dwordx4 %0, %3, off sc0 sc1\n\t"
                    "global_load_dwordx4 %1, %4, off sc0 sc1\n\t"
                    "global_load_dwordx4 %2, %5, off sc0 sc1\n\t"
                    "s_waitcnt vmcnt(0)"
                    : "=&v"(a0), "=&v"(a1), "=&v"(a2)
                    : "v"(p0), "v"(p1), "v"(p2)
                    : "memory");
                mm = (a0[0] ^ tgt) | (a0[1] ^ tgt) | (a0[2] ^ tgt) | (a0[3] ^ tgt)
                   | (a1[0] ^ tgt) | (a1[1] ^ tgt) | (a1[2] ^ tgt) | (a1[3] ^ tgt);
                if (has2)
                    mm |= (a2[0] ^ tgt) | (a2[1] ^ tgt) | (a2[2] ^ tgt) | (a2[3] ^ tgt);
            } while (mm & 0xffffu);
        }

        // ---- strip tags -> h bf16 into LDS ----
        {
            ushort4v v0 = {(unsigned short)(a0[0] >> 16), (unsigned short)(a0[1] >> 16),
                           (unsigned short)(a0[2] >> 16), (unsigned short)(a0[3] >> 16)};
            ushort4v v1 = {(unsigned short)(a1[0] >> 16), (unsigned short)(a1[1] >> 16),
                           (unsigned short)(a1[2] >> 16), (unsigned short)(a1[3] >> 16)};
            *(ushort4v*)&hbl[slot][b0][k0] = v0;
            *(ushort4v*)&hbl[slot][b1][k1] = v1;
            if (has2) {
                ushort4v v2 = {(unsigned short)(a2[0] >> 16), (unsigned short)(a2[1] >> 16),
                               (unsigned short)(a2[2] >> 16), (unsigned short)(a2[3] >> 16)};
                *(ushort4v*)&hbl[slot][b2][k2] = v2;
            }
        }

        __syncthreads();   // h LDS + (prev-step) x LDS ready for MFMA

        // ---- MFMA: x-half 3-term (s=0..9), h-half 2-term (s=10..19) ----
        f32x4 acc0 = {0.f, 0.f, 0.f, 0.f};
        f32x4 acc1 = {0.f, 0.f, 0.f, 0.f};
        f32x4 acc2 = {0.f, 0.f, 0.f, 0.f};
        {
            const unsigned short* bxh = &xb[slot][0][col][q * 8];
            const unsigned short* bxl = &xb[slot][1][col][q * 8];
            const unsigned short* bhp = &hbl[slot][col][q * 8];
            #pragma unroll
            for (int s = 0; s < 10; ++s) {
                short8 bh = *(const short8*)(bxh + s * 32);
                short8 bl = *(const short8*)(bxl + s * 32);
                acc0 = __builtin_amdgcn_mfma_f32_16x16x32_bf16(ahi[s], bh, acc0, 0, 0, 0);
                acc1 = __builtin_amdgcn_mfma_f32_16x16x32_bf16(alo[s], bh, acc1, 0, 0, 0);
                acc2 = __builtin_amdgcn_mfma_f32_16x16x32_bf16(ahi[s], bl, acc2, 0, 0, 0);
            }
            #pragma unroll
            for (int s = 0; s < 10; ++s) {
                short8 bh = *(const short8*)(bhp + s * 32);
                acc0 = __builtin_amdgcn_mfma_f32_16x16x32_bf16(ahi[10 + s], bh, acc0, 0, 0, 0);
                acc1 = __builtin_amdgcn_mfma_f32_16x16x32_bf16(alo[10 + s], bh, acc1, 0, 0, 0);
            }
        }

        // ---- gate math ----
        float p[4];
        #pragma unroll
        for (int v = 0; v < 4; ++v) p[v] = acc0[v] + acc1[v] + acc2[v] + bias4[v];
        float gi = sat01(0.2f * p[0] + 0.5f);
        float gf = sat01(0.2f * p[1] + 0.5f);
        float gg = clamp1(p[2]);
        float go = sat01(0.2f * p[3] + 0.5f);
        c_state = gf * c_state + gi * gg;
        float h1 = go * clamp1(c_state);

        // ---- publish h(t+1): one dword, no drain, no flag ----
        uint32_t dpk = ((uint32_t)f2bf(h1) << 16) | ((uint32_t)(t + 2) & 0xffffu);
        st_dword_l3(hSelf0 + (size_t)slotn * SSZ, dpk);

        // out (cached path)
        out[(size_t)t * SSZ + (size_t)bOut * HDIM + jOut] = h1;

        // x(t+1) -> LDS slotn (consumed after next barrier)
        if (havex) {
            cvt_store(&xb[slotn][0][b0][k0], &xb[slotn][1][b0][k0], xr0);
            cvt_store(&xb[slotn][0][b1][k1], &xb[slotn][1][b1][k1], xr1);
            if (has2) cvt_store(&xb[slotn][0][b2][k2], &xb[slotn][1][b2][k2], xr2);
        }
    }
}

extern "C" void kernel_launch(void* const* d_in, const int* in_sizes, int n_in,
                              void* d_out, int out_size, void* d_ws, size_t ws_size,
                              hipStream_t stream) {
    const float* x   = (const float*)d_in[0];
    const float* wih = (const float*)d_in[1];
    const float* whh = (const float*)d_in[2];
    const float* bih = (const float*)d_in[3];
    const float* bhh = (const float*)d_in[4];
    float* out = (float*)d_out;

    uint32_t* hb32 = (uint32_t*)d_ws;   // 2 slots x 10240 dwords = 80 KiB

    // clear stale tags from previous replay (t=1999 target 2000 would alias)
    hipMemsetAsync(hb32, 0, (size_t)2 * SSZ * 4, stream);

    void* args[] = {(void*)&x, (void*)&wih, (void*)&whh, (void*)&bih, (void*)&bhh,
                    (void*)&out, (void*)&hb32};
    hipError_t e = hipLaunchCooperativeKernel((const void*)hard_lstm, dim3(NWG), dim3(NTH),
                                              args, 0, stream);
    if (e != hipSuccess) {
        hipLaunchKernelGGL(hard_lstm, dim3(NWG), dim3(NTH), 0, stream,
                           x, wih, whh, bih, bhh, out, hb32);
    }
}